// Round 12
// baseline (138.583 us; speedup 1.0000x reference)
//
#include <hip/hip_runtime.h>
#include <math.h>

// Problem constants (MSDeformMatchV2HeaderAttn)
#define BB 2
#define LQ 1024
#define DM 256
#define NH 8
#define DH 32
#define NL 4
#define HWsp 1024   // 32*32
#define LIN 4096
#define K9 36
#define NGRP (BB * NH * NL * LQ)  // 65536 groups

typedef short bf16x8 __attribute__((ext_vector_type(8)));
typedef float f32x4 __attribute__((ext_vector_type(4)));

// round-to-nearest-even fp32 -> bf16 bits
__device__ __forceinline__ ushort bf16rn(float x) {
  unsigned u = __float_as_uint(x);
  unsigned r = (u + 0x7FFFu + ((u >> 16) & 1u)) >> 16;
  return (ushort)r;
}
__device__ __forceinline__ float bf16tof(ushort h) {
  return __uint_as_float(((unsigned)h) << 16);
}

// stable insert (value desc; ascending id scan => lower id wins ties)
#define INSERT4S(S, val, index)                                               \
  {                                                                           \
    const float v_ = (val);                                                   \
    const int ix_ = (index);                                                  \
    if (v_ > v3##S) {                                                         \
      if (v_ > v1##S) {                                                       \
        if (v_ > v0##S) {                                                     \
          v3##S = v2##S; i3##S = i2##S; v2##S = v1##S; i2##S = i1##S;         \
          v1##S = v0##S; i1##S = i0##S; v0##S = v_; i0##S = ix_;              \
        } else {                                                              \
          v3##S = v2##S; i3##S = i2##S; v2##S = v1##S; i2##S = i1##S;         \
          v1##S = v_; i1##S = ix_;                                            \
        }                                                                     \
      } else {                                                                \
        if (v_ > v2##S) {                                                     \
          v3##S = v2##S; i3##S = i2##S; v2##S = v_; i2##S = ix_;              \
        } else {                                                              \
          v3##S = v_; i3##S = ix_;                                            \
        }                                                                     \
      }                                                                       \
    }                                                                         \
  }

#define LEXGT(v_, ix_, vv, ii) (((v_) > (vv)) || ((v_) == (vv) && (ix_) < (ii)))

// lex-aware insert for recovery (candidates arrive in quad-rank order)
#define INSERT4LEX(val, index)                                               \
  {                                                                          \
    const float v_ = (val);                                                  \
    const int ix_ = (index);                                                 \
    if (LEXGT(v_, ix_, rv3, ri3)) {                                          \
      if (LEXGT(v_, ix_, rv1, ri1)) {                                        \
        if (LEXGT(v_, ix_, rv0, ri0)) {                                      \
          rv3 = rv2; ri3 = ri2; rv2 = rv1; ri2 = ri1; rv1 = rv0; ri1 = ri0;  \
          rv0 = v_; ri0 = ix_;                                               \
        } else {                                                             \
          rv3 = rv2; ri3 = ri2; rv2 = rv1; ri2 = ri1; rv1 = v_; ri1 = ix_;   \
        }                                                                    \
      } else {                                                               \
        if (LEXGT(v_, ix_, rv2, ri2)) {                                      \
          rv3 = rv2; ri3 = ri2; rv2 = v_; ri2 = ix_;                         \
        } else {                                                             \
          rv3 = v_; ri3 = ix_;                                               \
        }                                                                    \
      }                                                                      \
    }                                                                        \
  }

// a := lexmax(a, b)  under (value desc, index asc)
#define LMAX(av, ai, bv, bi)                                        \
  {                                                                 \
    const bool g_ = ((av) > (bv)) || ((av) == (bv) && (ai) < (bi)); \
    if (!g_) { (av) = (bv); (ai) = (bi); }                          \
  }
// compare-exchange: order (a,b) so a >=lex b
#define CEX(av, ai, bv, bi)                                         \
  {                                                                 \
    const bool g_ = ((av) > (bv)) || ((av) == (bv) && (ai) < (bi)); \
    const float tv_ = g_ ? (av) : (bv);                             \
    const int ti_ = g_ ? (ai) : (bi);                               \
    (bv) = g_ ? (bv) : (av); (bi) = g_ ? (bi) : (ai);               \
    (av) = tv_; (ai) = ti_;                                         \
  }

// per-plane ushort stride of the presplit buffer
#define PSTRIDE ((size_t)BB * NL * NH * 1024 * 32)  // 2,097,152

// ---------------------------------------------------------------------------
// Kernel 0: one-shot bf16x3 split of value, head-major layout:
// vs[part][n][l][h][row(1024)][32] ushort.
// ---------------------------------------------------------------------------
__global__ __launch_bounds__(256) void vsplit_kernel(
    const float* __restrict__ value, ushort* __restrict__ vs) {
  const int T = blockIdx.x * 256 + threadIdx.x;  // < 262144
  const int flat = T << 3;
  const int n = flat >> 20;
  const int rem = flat & 0xFFFFF;
  const int lin = rem >> 8;
  const int d0 = rem & 255;
  const int l = lin >> 10, row = lin & 1023;
  const int h = d0 >> 5, dd = d0 & 31;

  const float* src = value + (size_t)flat;
  float xf[8];
  *(float4*)&xf[0] = *(const float4*)src;
  *(float4*)&xf[4] = *(const float4*)(src + 4);

  ushort uh[8], ul[8], ul2[8];
  #pragma unroll
  for (int j = 0; j < 8; ++j) {
    const float x = xf[j];
    const ushort h1 = bf16rn(x);
    const float r1 = x - bf16tof(h1);
    const ushort h2 = bf16rn(r1);
    const float r2 = r1 - bf16tof(h2);
    uh[j] = h1; ul[j] = h2; ul2[j] = bf16rn(r2);
  }
  const size_t ob = ((((size_t)((n * NL + l) * NH + h)) << 10) + row) * 32 + dd;
  *(bf16x8*)(vs + 0 * PSTRIDE + ob) =
      (bf16x8){(short)uh[0], (short)uh[1], (short)uh[2], (short)uh[3],
               (short)uh[4], (short)uh[5], (short)uh[6], (short)uh[7]};
  *(bf16x8*)(vs + 1 * PSTRIDE + ob) =
      (bf16x8){(short)ul[0], (short)ul[1], (short)ul[2], (short)ul[3],
               (short)ul[4], (short)ul[5], (short)ul[6], (short)ul[7]};
  *(bf16x8*)(vs + 2 * PSTRIDE + ob) =
      (bf16x8){(short)ul2[0], (short)ul2[1], (short)ul2[2], (short)ul2[3],
               (short)ul2[4], (short)ul2[5], (short)ul2[6], (short)ul2[7]};
}

// helper: build bf16x3 fragments for one Q row-slice (8 floats)
#define MAKE_Q_FRAGS(QF, QHI, QLO, QLO2, QP)                                  \
  {                                                                           \
    *(float4*)&QF[0] = *(const float4*)(QP);                                  \
    *(float4*)&QF[4] = *(const float4*)((QP) + 4);                            \
    ushort uh[8], ul[8], ul2[8];                                              \
    _Pragma("unroll")                                                         \
    for (int j = 0; j < 8; ++j) {                                             \
      const float x = QF[j];                                                  \
      const ushort h1 = bf16rn(x);                                            \
      const float r1 = x - bf16tof(h1);                                       \
      const ushort h2 = bf16rn(r1);                                           \
      const float r2 = r1 - bf16tof(h2);                                      \
      uh[j] = h1; ul[j] = h2; ul2[j] = bf16rn(r2);                            \
    }                                                                         \
    QHI = (bf16x8){(short)uh[0], (short)uh[1], (short)uh[2], (short)uh[3],    \
                   (short)uh[4], (short)uh[5], (short)uh[6], (short)uh[7]};   \
    QLO = (bf16x8){(short)ul[0], (short)ul[1], (short)ul[2], (short)ul[3],    \
                   (short)ul[4], (short)ul[5], (short)ul[6], (short)ul[7]};   \
    QLO2 = (bf16x8){(short)ul2[0], (short)ul2[1], (short)ul2[2], (short)ul2[3],\
                    (short)ul2[4], (short)ul2[5], (short)ul2[6], (short)ul2[7]};\
  }

// 6-term bf16x3 MFMA product, smallest-first (validated R5-R10 ordering)
#define MFMA6(ACC, AHI, ALO, ALO2, QHI, QLO, QLO2)                            \
  {                                                                           \
    ACC = __builtin_amdgcn_mfma_f32_16x16x32_bf16(ALO2, QHI, ACC, 0, 0, 0);   \
    ACC = __builtin_amdgcn_mfma_f32_16x16x32_bf16(AHI, QLO2, ACC, 0, 0, 0);   \
    ACC = __builtin_amdgcn_mfma_f32_16x16x32_bf16(ALO, QLO, ACC, 0, 0, 0);    \
    ACC = __builtin_amdgcn_mfma_f32_16x16x32_bf16(ALO, QHI, ACC, 0, 0, 0);    \
    ACC = __builtin_amdgcn_mfma_f32_16x16x32_bf16(AHI, QLO, ACC, 0, 0, 0);    \
    ACC = __builtin_amdgcn_mfma_f32_16x16x32_bf16(AHI, QHI, ACC, 0, 0, 0);    \
  }

// exact fp32 recovery of the 16 candidate k's of 4 quads, lex top-4
#define RECOVERY_BLOCK(QF, I0, I1, I2, I3)                               \
  float rv0 = -INFINITY, rv1 = -INFINITY, rv2 = -INFINITY,               \
        rv3 = -INFINITY;                                                 \
  int ri0 = 0, ri1 = 0, ri2 = 0, ri3 = 0;                                \
  {                                                                      \
    int cq[4] = {I0, I1, I2, I3};                                        \
    _Pragma("unroll")                                                    \
    for (int qq = 0; qq < 4; ++qq) {                                     \
      _Pragma("unroll")                                                  \
      for (int j = 0; j < 4; ++j) {                                      \
        const int k = (cq[qq] << 2) + j;                                 \
        const float* vf = vbase + (size_t)k * DM + (g << 3);             \
        const float4 a0 = *(const float4*)vf;                            \
        const float4 a1 = *(const float4*)(vf + 4);                      \
        float p = QF[0] * a0.x;                                          \
        p = fmaf(QF[1], a0.y, p);                                        \
        p = fmaf(QF[2], a0.z, p);                                        \
        p = fmaf(QF[3], a0.w, p);                                        \
        p = fmaf(QF[4], a1.x, p);                                        \
        p = fmaf(QF[5], a1.y, p);                                        \
        p = fmaf(QF[6], a1.z, p);                                        \
        p = fmaf(QF[7], a1.w, p);                                        \
        p += __shfl_xor(p, 16);                                          \
        p += __shfl_xor(p, 32);                                          \
        INSERT4LEX(p, k);                                                \
      }                                                                  \
    }                                                                    \
  }

// butterfly lex merge of a quad top-4 list across lanes 16/32
#define MERGE1632(V0, I0, V1, I1, V2, I2, V3, I3)                        \
  _Pragma("unroll")                                                      \
  for (int m = 16; m < 64; m <<= 1) {                                    \
    const float b0 = __shfl_xor(V0, m);                                  \
    const float b1 = __shfl_xor(V1, m);                                  \
    const float b2 = __shfl_xor(V2, m);                                  \
    const float b3 = __shfl_xor(V3, m);                                  \
    const int j0 = __shfl_xor(I0, m);                                    \
    const int j1 = __shfl_xor(I1, m);                                    \
    const int j2 = __shfl_xor(I2, m);                                    \
    const int j3 = __shfl_xor(I3, m);                                    \
    LMAX(V0, I0, b3, j3);                                                \
    LMAX(V1, I1, b2, j2);                                                \
    LMAX(V2, I2, b1, j1);                                                \
    LMAX(V3, I3, b0, j0);                                                \
    CEX(V0, I0, V2, I2);                                                 \
    CEX(V1, I1, V3, I3);                                                 \
    CEX(V0, I0, V1, I1);                                                 \
    CEX(V2, I2, V3, I3);                                                 \
  }

// ---------------------------------------------------------------------------
// Kernel 1 (v11): corr + stable top-4, presplit LDS staging, TWO q-tiles per
// wave, generalized k-split SPLIT in {1,2,4}. SPLIT=4: each block scans 4
// chunks (256 k), grid = (8*4, 4, 16) = 2048 blocks -> 8 blocks/CU, 100%
// wave-slot occupancy. Quad tournament + fp32 recovery (R8-validated).
// Block covers q [qc*128, qc*128+128); wave w owns q-tiles (qc*8+2w, +1).
// ---------------------------------------------------------------------------
template <int SPLIT>
__global__ __launch_bounds__(256) void corr_topk2_kernel(
    const float* __restrict__ query, const float* __restrict__ value,
    const ushort* __restrict__ vs, int* __restrict__ idx_out,
    float4* __restrict__ pval, int4* __restrict__ pidx) {
  __shared__ ushort hiL[64][32];
  __shared__ ushort loL[64][32];
  __shared__ ushort lo2L[64][32];

  constexpr int LS = (SPLIT == 4) ? 2 : (SPLIT == 2) ? 1 : 0;
  constexpr int CH = 16 / SPLIT;  // chunks per block

  const int tid = threadIdx.x;
  const int nh = blockIdx.z;  // n*8+h
  const int n = nh >> 3, h = nh & 7;
  const int l = blockIdx.y;
  const int qc = (int)blockIdx.x >> LS;
  const int part = (int)blockIdx.x & (SPLIT - 1);
  const int c0 = part * CH;
  const int c1 = c0 + CH;
  const int w = tid >> 6, L = tid & 63;
  const int qtA = (qc << 3) + (w << 1);  // 16-q tile indices
  const int qtB = qtA + 1;
  const int r16 = L & 15, g = L >> 4;  // C: col=r16(q), row-group g

  // ---- Q fragments for both tiles (persistent) ----
  float qfA[8], qfB[8];
  bf16x8 qhiA, qloA, qlo2A, qhiB, qloB, qlo2B;
  {
    const float* qpA =
        query + (size_t)(n * LQ + (qtA << 4) + r16) * DM + h * DH + (g << 3);
    MAKE_Q_FRAGS(qfA, qhiA, qloA, qlo2A, qpA)
    const float* qpB = qpA + (size_t)16 * DM;  // qtB = qtA+1 -> +16 rows
    MAKE_Q_FRAGS(qfB, qhiB, qloB, qlo2B, qpB)
  }

  // quad tournament state, one per q-tile
  float v0A = -INFINITY, v1A = -INFINITY, v2A = -INFINITY, v3A = -INFINITY;
  int i0A = 0, i1A = 0, i2A = 0, i3A = 0;
  float v0B = -INFINITY, v1B = -INFINITY, v2B = -INFINITY, v3B = -INFINITY;
  int i0B = 0, i1B = 0, i2B = 0, i3B = 0;

  // staging mapping (R8-validated, 0 measured conflicts)
  const int srow = tid >> 2, s = tid & 3;
  const int wslot = (s ^ ((srow >> 1) & 3)) << 3;
  const int rslot = (g ^ ((r16 >> 1) & 3)) << 3;
  const ushort* psbase =
      vs + ((((size_t)((n * NL + l) * NH + h)) << 10)) * 32;
  const float* vbase = value + (size_t)(n * LIN + l * HWsp) * DM + h * DH;

  for (int c = c0; c < c1; ++c) {
    {
      const size_t off = ((size_t)((c << 6) + srow)) * 32 + (s << 3);
      *(bf16x8*)&hiL[srow][wslot] = *(const bf16x8*)(psbase + off);
      *(bf16x8*)&loL[srow][wslot] = *(const bf16x8*)(psbase + PSTRIDE + off);
      *(bf16x8*)&lo2L[srow][wslot] = *(const bf16x8*)(psbase + 2 * PSTRIDE + off);
    }
    __syncthreads();

    #pragma unroll
    for (int t = 0; t < 4; ++t) {
      const int row = (t << 4) + r16;
      const bf16x8 ahi = *(const bf16x8*)&hiL[row][rslot];
      const bf16x8 alo = *(const bf16x8*)&loL[row][rslot];
      const bf16x8 alo2 = *(const bf16x8*)&lo2L[row][rslot];
      f32x4 accA = {0.f, 0.f, 0.f, 0.f};
      f32x4 accB = {0.f, 0.f, 0.f, 0.f};
      MFMA6(accA, ahi, alo, alo2, qhiA, qloA, qlo2A)
      MFMA6(accB, ahi, alo, alo2, qhiB, qloB, qlo2B)
      const int qd = (c << 4) + (t << 2) + g;  // quad id = k/4
      const float qmA = fmaxf(fmaxf(accA[0], accA[1]), fmaxf(accA[2], accA[3]));
      const float qmB = fmaxf(fmaxf(accB[0], accB[1]), fmaxf(accB[2], accB[3]));
      INSERT4S(A, qmA, qd);
      INSERT4S(B, qmB, qd);
    }
    __syncthreads();
  }

  // merge quad lists across the 4 row-groups (lanes 16/32)
  MERGE1632(v0A, i0A, v1A, i1A, v2A, i2A, v3A, i3A)
  MERGE1632(v0B, i0B, v1B, i1B, v2B, i2B, v3B, i3B)

  // recovery + output, tile A then tile B
  {
    RECOVERY_BLOCK(qfA, i0A, i1A, i2A, i3A)
    if (L < 16) {
      const int q = (qtA << 4) + L;
      const size_t gi = (((size_t)nh * NL + l) << 10) + q;
      if (SPLIT > 1) {
        pval[gi * SPLIT + part] = make_float4(rv0, rv1, rv2, rv3);
        pidx[gi * SPLIT + part] = make_int4(ri0, ri1, ri2, ri3);
      } else {
        ((int4*)idx_out)[gi] = make_int4(ri0, ri1, ri2, ri3);
      }
    }
  }
  {
    RECOVERY_BLOCK(qfB, i0B, i1B, i2B, i3B)
    if (L < 16) {
      const int q = (qtB << 4) + L;
      const size_t gi = (((size_t)nh * NL + l) << 10) + q;
      if (SPLIT > 1) {
        pval[gi * SPLIT + part] = make_float4(rv0, rv1, rv2, rv3);
        pidx[gi * SPLIT + part] = make_int4(ri0, ri1, ri2, ri3);
      } else {
        ((int4*)idx_out)[gi] = make_int4(ri0, ri1, ri2, ri3);
      }
    }
  }
}

// ---------------------------------------------------------------------------
// Kernel 1-fallback (R8 LDS path, in-kernel conversion, 1 q-tile/wave).
// ---------------------------------------------------------------------------
template <int SPLIT>
__global__ __launch_bounds__(256) void corr_topk_lds_kernel(
    const float* __restrict__ query, const float* __restrict__ value,
    int* __restrict__ idx_out, float4* __restrict__ pval,
    int4* __restrict__ pidx) {
  __shared__ ushort hiL[64][32];
  __shared__ ushort loL[64][32];
  __shared__ ushort lo2L[64][32];

  const int tid = threadIdx.x;
  const int nh = blockIdx.z;
  const int n = nh >> 3, h = nh & 7;
  const int l = blockIdx.y;
  const int qc = (SPLIT == 2) ? ((int)blockIdx.x >> 1) : (int)blockIdx.x;
  const int half = (SPLIT == 2) ? ((int)blockIdx.x & 1) : 0;
  const int c0 = (SPLIT == 2) ? (half << 3) : 0;
  const int c1 = (SPLIT == 2) ? (c0 + 8) : 16;
  const int w = tid >> 6, L = tid & 63;
  const int qtile = (qc << 2) + w;
  const int r16 = L & 15, g = L >> 4;

  float qfA[8];
  bf16x8 qhiA, qloA, qlo2A;
  {
    const float* qp =
        query + (size_t)(n * LQ + (qtile << 4) + r16) * DM + h * DH + (g << 3);
    MAKE_Q_FRAGS(qfA, qhiA, qloA, qlo2A, qp)
  }

  float v0A = -INFINITY, v1A = -INFINITY, v2A = -INFINITY, v3A = -INFINITY;
  int i0A = 0, i1A = 0, i2A = 0, i3A = 0;

  const int srow = tid >> 2, s = tid & 3;
  const int wslot = (s ^ ((srow >> 1) & 3)) << 3;
  const int rslot = (g ^ ((r16 >> 1) & 3)) << 3;
  const float* vbase = value + (size_t)(n * LIN + l * HWsp) * DM + h * DH;

  for (int c = c0; c < c1; ++c) {
    {
      const float* vp = vbase + (size_t)((c << 6) + srow) * DM + (s << 3);
      float xf[8];
      *(float4*)&xf[0] = *(const float4*)vp;
      *(float4*)&xf[4] = *(const float4*)(vp + 4);
      ushort uh[8], ul[8], ul2[8];
      #pragma unroll
      for (int j = 0; j < 8; ++j) {
        const float x = xf[j];
        const ushort h1 = bf16rn(x);
        const float r1 = x - bf16tof(h1);
        const ushort h2 = bf16rn(r1);
        const float r2 = r1 - bf16tof(h2);
        uh[j] = h1; ul[j] = h2; ul2[j] = bf16rn(r2);
      }
      *(bf16x8*)&hiL[srow][wslot] =
          (bf16x8){(short)uh[0], (short)uh[1], (short)uh[2], (short)uh[3],
                   (short)uh[4], (short)uh[5], (short)uh[6], (short)uh[7]};
      *(bf16x8*)&loL[srow][wslot] =
          (bf16x8){(short)ul[0], (short)ul[1], (short)ul[2], (short)ul[3],
                   (short)ul[4], (short)ul[5], (short)ul[6], (short)ul[7]};
      *(bf16x8*)&lo2L[srow][wslot] =
          (bf16x8){(short)ul2[0], (short)ul2[1], (short)ul2[2], (short)ul2[3],
                   (short)ul2[4], (short)ul2[5], (short)ul2[6], (short)ul2[7]};
    }
    __syncthreads();

    #pragma unroll
    for (int t = 0; t < 4; ++t) {
      const int row = (t << 4) + r16;
      const bf16x8 ahi = *(const bf16x8*)&hiL[row][rslot];
      const bf16x8 alo = *(const bf16x8*)&loL[row][rslot];
      const bf16x8 alo2 = *(const bf16x8*)&lo2L[row][rslot];
      f32x4 accA = {0.f, 0.f, 0.f, 0.f};
      MFMA6(accA, ahi, alo, alo2, qhiA, qloA, qlo2A)
      const float qm = fmaxf(fmaxf(accA[0], accA[1]), fmaxf(accA[2], accA[3]));
      const int qd = (c << 4) + (t << 2) + g;
      INSERT4S(A, qm, qd);
    }
    __syncthreads();
  }

  MERGE1632(v0A, i0A, v1A, i1A, v2A, i2A, v3A, i3A)

  RECOVERY_BLOCK(qfA, i0A, i1A, i2A, i3A)

  if (L < 16) {
    const int q = (qtile << 4) + L;
    const size_t gi = (((size_t)nh * NL + l) << 10) + q;
    if (SPLIT == 2) {
      pval[gi * 2 + half] = make_float4(rv0, rv1, rv2, rv3);
      pidx[gi * 2 + half] = make_int4(ri0, ri1, ri2, ri3);
    } else {
      ((int4*)idx_out)[gi] = make_int4(ri0, ri1, ri2, ri3);
    }
  }
}

// ---------------------------------------------------------------------------
// Kernel 1b: fold SPLIT sorted partial top-4 lists per group (pairwise
// bitonic lex merge, validated for the 2-list case R4-R10).
// ---------------------------------------------------------------------------
template <int SPLIT>
__global__ __launch_bounds__(256) void merge_topk_kernel(
    const float4* __restrict__ pval, const int4* __restrict__ pidx,
    int* __restrict__ idx_out) {
  const int t = blockIdx.x * 256 + threadIdx.x;  // < NGRP
  float4 av = pval[(size_t)t * SPLIT];
  int4 ai = pidx[(size_t)t * SPLIT];
  float w0 = av.x, w1 = av.y, w2 = av.z, w3 = av.w;
  int m0 = ai.x, m1 = ai.y, m2 = ai.z, m3 = ai.w;
  #pragma unroll
  for (int s = 1; s < SPLIT; ++s) {
    const float4 bv = pval[(size_t)t * SPLIT + s];
    const int4 bi = pidx[(size_t)t * SPLIT + s];
    LMAX(w0, m0, bv.w, bi.w);
    LMAX(w1, m1, bv.z, bi.z);
    LMAX(w2, m2, bv.y, bi.y);
    LMAX(w3, m3, bv.x, bi.x);
    CEX(w0, m0, w2, m2);
    CEX(w1, m1, w3, m3);
    CEX(w0, m0, w1, m1);
    CEX(w2, m2, w3, m3);
  }
  ((int4*)idx_out)[t] = make_int4(m0, m1, m2, m3);
}

// ---------------------------------------------------------------------------
// Kernel 2: loc output. res=clip(idx+delta,0,961); loc=(res>>5, res&31)/32.
// ---------------------------------------------------------------------------
__global__ __launch_bounds__(256) void loc_kernel(const int* __restrict__ idx_buf,
                                                  float* __restrict__ loc) {
  const int t = blockIdx.x * 256 + threadIdx.x;  // < 2359296
  const int k = t % 36;
  int rest = t / 36;
  const int l = rest & 3; rest >>= 2;
  const int h = rest & 7; rest >>= 3;
  const int q = rest & 1023;
  const int n = rest >> 10;
  const int p = k & 3, dd = k >> 2;  // delta-major: k = dd*4 + p
  const int idx = idx_buf[(((((n << 3) + h) * NL + l) << 10) + q) * 4 + p];
  const int delta = ((dd / 3) - 1) * 32 + (dd % 3) - 1;
  int res = idx + delta;
  res = min(max(res, 0), 961);
  const int W = res >> 5, H = res & 31;
  ((float2*)loc)[t] = make_float2((float)W * 0.03125f, (float)H * 0.03125f);
}

// ---------------------------------------------------------------------------
// Kernel 3: gather+average, wave-per-(n,q,h,l) (R7/R8-validated).
// ---------------------------------------------------------------------------
__global__ __launch_bounds__(256) void gather_kernel(
    const float* __restrict__ value, const int* __restrict__ idx_buf,
    float* __restrict__ acc_out) {
  __shared__ float4 red[NL][8];
  const int bh = blockIdx.x;  // (n*1024+q)*8 + h
  const int h = bh & 7;
  const int nq = bh >> 3;
  const int n = nq >> 10, q = nq & 1023;
  const int tid = threadIdx.x;
  const int l = tid >> 6;  // wave = level
  const int L = tid & 63;
  const int cp = L >> 3, d4 = L & 7;

  const int4 id4 =
      ((const int4*)idx_buf)[((((size_t)((n << 3) + h)) * NL + l) << 10) + q];
  const float4* vb4 =
      (const float4*)(value + (size_t)(n * LIN + l * HWsp) * DM + h * DH) + d4;

  float4 a = make_float4(0.f, 0.f, 0.f, 0.f);
  #pragma unroll
  for (int p = 0; p < 4; ++p) {
    const int idx = (p == 0) ? id4.x : (p == 1) ? id4.y : (p == 2) ? id4.z : id4.w;
    const int H0 = idx & 31, W0 = idx >> 5;
    if (H0 >= 2 && H0 <= 30 && W0 >= 2 && W0 <= 28) {
      const int idxT = (H0 << 5) + W0;
      const int c0i = cp << 1;
      const int ax0 = c0i & 3, ay = c0i >> 2;
      const int r0 = idxT + (ax0 - 2) * 32 + (ay - 2);
      const float wy = (ay == 1 || ay == 2) ? 2.f : 1.f;
      const float f0 = ((ax0 == 2) ? 2.f : 1.f) * wy;
      const float f1 = ((ax0 + 1 == 1) ? 2.f : 1.f) * wy;
      const float4 va = vb4[(size_t)r0 * 64];
      const float4 vbb = vb4[(size_t)(r0 + 32) * 64];
      a.x += f0 * va.x + f1 * vbb.x;
      a.y += f0 * va.y + f1 * vbb.y;
      a.z += f0 * va.z + f1 * vbb.z;
      a.w += f0 * va.w + f1 * vbb.w;
    } else {
      #pragma unroll
      for (int it = 0; it < 5; ++it) {
        const int u = cp + (it << 3);
        const int cell = u >> 2, corner = u & 3;
        const int dy = (cell >= 3) + (cell >= 6) - 1;
        const int dx = cell - (dy + 1) * 3 - 1;
        int res = idx + dy * 32 + dx;
        res = min(max(res, 0), 961);
        const int W = res >> 5, H = res & 31;
        const int cw = corner & 1, ch = corner >> 1;
        const bool ok = (u < 36) && (W >= cw) && (H >= ch);
        const int row = ok ? (((H - ch) << 5) + (W - cw)) : 0;
        const float wgt = ok ? 1.f : 0.f;
        const float4 v = vb4[(size_t)row * 64];
        a.x += wgt * v.x;
        a.y += wgt * v.y;
        a.z += wgt * v.z;
        a.w += wgt * v.w;
      }
    }
  }

  #pragma unroll
  for (int m = 8; m < 64; m <<= 1) {
    a.x += __shfl_xor(a.x, m);
    a.y += __shfl_xor(a.y, m);
    a.z += __shfl_xor(a.z, m);
    a.w += __shfl_xor(a.w, m);
  }
  if (L < 8) red[l][L] = a;
  __syncthreads();
  if (tid < 8) {
    const float4 s0 = red[0][tid], s1 = red[1][tid], s2 = red[2][tid],
                 s3 = red[3][tid];
    float4 o;
    o.x = (s0.x + s1.x + s2.x + s3.x) * (1.0f / 576.0f);
    o.y = (s0.y + s1.y + s2.y + s3.y) * (1.0f / 576.0f);
    o.z = (s0.z + s1.z + s2.z + s3.z) * (1.0f / 576.0f);
    o.w = (s0.w + s1.w + s2.w + s3.w) * (1.0f / 576.0f);
    ((float4*)(acc_out + (size_t)nq * DM + h * DH))[tid] = o;
  }
}

// ---------------------------------------------------------------------------
// Kernel 4: out = acc @ W^T + b.  256 blocks x 256 threads, 8 q-rows/block.
// ---------------------------------------------------------------------------
__global__ __launch_bounds__(256) void proj_kernel(
    const float* __restrict__ acc_in, const float* __restrict__ W,
    const float* __restrict__ bias, float* __restrict__ out) {
  __shared__ float la[8][256];
  const int qb = blockIdx.x << 3;
  const int tid = threadIdx.x;
  for (int i = tid; i < 8 * 256; i += 256)
    la[i >> 8][i & 255] = acc_in[((size_t)qb << 8) + i];
  __syncthreads();
  const float* wrow = W + (size_t)tid * 256;
  float s0 = 0.f, s1 = 0.f, s2 = 0.f, s3 = 0.f, s4 = 0.f, s5 = 0.f, s6 = 0.f, s7 = 0.f;
  for (int c0 = 0; c0 < 256; c0 += 4) {
    const float4 wv = *(const float4*)(wrow + c0);
    #define PROJ_STEP(qi, sreg)                                   \
      {                                                           \
        const float4 av = *(const float4*)&la[qi][c0];            \
        sreg = fmaf(wv.x, av.x, sreg);                            \
        sreg = fmaf(wv.y, av.y, sreg);                            \
        sreg = fmaf(wv.z, av.z, sreg);                            \
        sreg = fmaf(wv.w, av.w, sreg);                            \
      }
    PROJ_STEP(0, s0) PROJ_STEP(1, s1) PROJ_STEP(2, s2) PROJ_STEP(3, s3)
    PROJ_STEP(4, s4) PROJ_STEP(5, s5) PROJ_STEP(6, s6) PROJ_STEP(7, s7)
    #undef PROJ_STEP
  }
  const float bj = bias[tid];
  out[(size_t)(qb + 0) * 256 + tid] = s0 + bj;
  out[(size_t)(qb + 1) * 256 + tid] = s1 + bj;
  out[(size_t)(qb + 2) * 256 + tid] = s2 + bj;
  out[(size_t)(qb + 3) * 256 + tid] = s3 + bj;
  out[(size_t)(qb + 4) * 256 + tid] = s4 + bj;
  out[(size_t)(qb + 5) * 256 + tid] = s5 + bj;
  out[(size_t)(qb + 6) * 256 + tid] = s6 + bj;
  out[(size_t)(qb + 7) * 256 + tid] = s7 + bj;
}

// ---------------------------------------------------------------------------
extern "C" void kernel_launch(void* const* d_in, const int* in_sizes, int n_in,
                              void* d_out, int out_size, void* d_ws, size_t ws_size,
                              hipStream_t stream) {
  (void)in_sizes; (void)n_in; (void)out_size;
  const float* query = (const float*)d_in[0];
  const float* value = (const float*)d_in[2];
  const float* opw = (const float*)d_in[5];
  const float* opb = (const float*)d_in[6];

  float* out = (float*)d_out;               // [2,1024,256]
  float* loc = out + (size_t)BB * LQ * DM;  // [2,1024,8,4,36,2]

  const size_t SPLITB = 3 * PSTRIDE * sizeof(ushort);        // 12.58 MB
  const size_t PART4B = (size_t)NGRP * 4 * 16;               // 4 MB each
  const size_t PART2B = (size_t)NGRP * 2 * 16;               // 2 MB each
  const size_t IDXB = (size_t)NGRP * 4 * sizeof(int);        // 1 MB
  const size_t ACCB = (size_t)BB * LQ * DM * sizeof(float);  // 2 MB

  if (ws_size >= SPLITB + 2 * PART4B + IDXB + ACCB) {
    // tier 1: presplit + k-split x4, 2 q-tiles/wave (2048 blocks, 8/CU)
    ushort* vsb = (ushort*)d_ws;
    float4* pval = (float4*)((char*)d_ws + SPLITB);
    int4* pidx = (int4*)((char*)d_ws + SPLITB + PART4B);
    int* idx_buf = (int*)((char*)d_ws + SPLITB + 2 * PART4B);
    float* acc_buf = (float*)((char*)d_ws + SPLITB + 2 * PART4B + IDXB);

    vsplit_kernel<<<dim3(1024), 256, 0, stream>>>(value, vsb);
    corr_topk2_kernel<4><<<dim3(32, NL, BB * NH), 256, 0, stream>>>(
        query, value, vsb, idx_buf, pval, pidx);
    merge_topk_kernel<4><<<dim3(NGRP / 256), 256, 0, stream>>>(pval, pidx,
                                                               idx_buf);
    loc_kernel<<<dim3((BB * LQ * NH * NL * K9) / 256), 256, 0, stream>>>(idx_buf, loc);
    gather_kernel<<<dim3(BB * LQ * NH), 256, 0, stream>>>(value, idx_buf, acc_buf);
    proj_kernel<<<dim3(BB * LQ / 8), 256, 0, stream>>>(acc_buf, opw, opb, out);
  } else if (ws_size >= SPLITB + 2 * PART2B + IDXB + ACCB) {
    // tier 2: presplit + k-split x2, 2 q-tiles/wave (R10 structure)
    ushort* vsb = (ushort*)d_ws;
    float4* pval = (float4*)((char*)d_ws + SPLITB);
    int4* pidx = (int4*)((char*)d_ws + SPLITB + PART2B);
    int* idx_buf = (int*)((char*)d_ws + SPLITB + 2 * PART2B);
    float* acc_buf = (float*)((char*)d_ws + SPLITB + 2 * PART2B + IDXB);

    vsplit_kernel<<<dim3(1024), 256, 0, stream>>>(value, vsb);
    corr_topk2_kernel<2><<<dim3(16, NL, BB * NH), 256, 0, stream>>>(
        query, value, vsb, idx_buf, pval, pidx);
    merge_topk_kernel<2><<<dim3(NGRP / 256), 256, 0, stream>>>(pval, pidx,
                                                               idx_buf);
    loc_kernel<<<dim3((BB * LQ * NH * NL * K9) / 256), 256, 0, stream>>>(idx_buf, loc);
    gather_kernel<<<dim3(BB * LQ * NH), 256, 0, stream>>>(value, idx_buf, acc_buf);
    proj_kernel<<<dim3(BB * LQ / 8), 256, 0, stream>>>(acc_buf, opw, opb, out);
  } else if (ws_size >= 2 * PART2B + IDXB + ACCB) {
    // tier 3: in-kernel conversion + k-split x2 (R8 structure)
    float4* pval = (float4*)d_ws;
    int4* pidx = (int4*)((char*)d_ws + PART2B);
    int* idx_buf = (int*)((char*)d_ws + 2 * PART2B);
    float* acc_buf = (float*)((char*)d_ws + 2 * PART2B + IDXB);

    corr_topk_lds_kernel<2><<<dim3(32, NL, BB * NH), 256, 0, stream>>>(
        query, value, idx_buf, pval, pidx);
    merge_topk_kernel<2><<<dim3(NGRP / 256), 256, 0, stream>>>(pval, pidx,
                                                               idx_buf);
    loc_kernel<<<dim3((BB * LQ * NH * NL * K9) / 256), 256, 0, stream>>>(idx_buf, loc);
    gather_kernel<<<dim3(BB * LQ * NH), 256, 0, stream>>>(value, idx_buf, acc_buf);
    proj_kernel<<<dim3(BB * LQ / 8), 256, 0, stream>>>(acc_buf, opw, opb, out);
  } else {
    // tier 4: minimal workspace
    int* idx_buf = (int*)d_ws;
    float* acc_buf = (float*)((char*)d_ws + IDXB);

    corr_topk_lds_kernel<1><<<dim3(16, NL, BB * NH), 256, 0, stream>>>(
        query, value, idx_buf, (float4*)nullptr, (int4*)nullptr);
    loc_kernel<<<dim3((BB * LQ * NH * NL * K9) / 256), 256, 0, stream>>>(idx_buf, loc);
    gather_kernel<<<dim3(BB * LQ * NH), 256, 0, stream>>>(value, idx_buf, acc_buf);
    proj_kernel<<<dim3(BB * LQ / 8), 256, 0, stream>>>(acc_buf, opw, opb, out);
  }
}

// Round 13
// 104.902 us; speedup vs baseline: 1.3211x; 1.3211x over previous
//
#include <hip/hip_runtime.h>
#include <math.h>

// Problem constants (MSDeformMatchV2HeaderAttn)
#define BB 2
#define LQ 1024
#define DM 256
#define NH 8
#define DH 32
#define NL 4
#define HWsp 1024   // 32*32
#define LIN 4096
#define K9 36
#define NGRP (BB * NH * NL * LQ)  // 65536 groups

typedef short bf16x8 __attribute__((ext_vector_type(8)));
typedef float f32x4 __attribute__((ext_vector_type(4)));

// round-to-nearest-even fp32 -> bf16 bits
__device__ __forceinline__ ushort bf16rn(float x) {
  unsigned u = __float_as_uint(x);
  unsigned r = (u + 0x7FFFu + ((u >> 16) & 1u)) >> 16;
  return (ushort)r;
}
__device__ __forceinline__ float bf16tof(ushort h) {
  return __uint_as_float(((unsigned)h) << 16);
}

// stable insert of one (val,id) into sorted-desc 4-list (strict >; ascending
// id scan order => lower id wins ties)
#define INSERT4(val, index)                                              \
  {                                                                      \
    const float v_ = (val);                                              \
    const int ix_ = (index);                                             \
    if (v_ > v3) {                                                       \
      if (v_ > v1) {                                                     \
        if (v_ > v0) {                                                   \
          v3 = v2; i3 = i2; v2 = v1; i2 = i1; v1 = v0; i1 = i0;          \
          v0 = v_; i0 = ix_;                                             \
        } else {                                                         \
          v3 = v2; i3 = i2; v2 = v1; i2 = i1; v1 = v_; i1 = ix_;         \
        }                                                                \
      } else {                                                           \
        if (v_ > v2) {                                                   \
          v3 = v2; i3 = i2; v2 = v_; i2 = ix_;                           \
        } else {                                                         \
          v3 = v_; i3 = ix_;                                             \
        }                                                                \
      }                                                                  \
    }                                                                    \
  }

// a := lexmax(a, b)  under (value desc, index asc)
#define LMAX(av, ai, bv, bi)                                        \
  {                                                                 \
    const bool g_ = ((av) > (bv)) || ((av) == (bv) && (ai) < (bi)); \
    if (!g_) { (av) = (bv); (ai) = (bi); }                          \
  }
// compare-exchange: order (a,b) so a >=lex b
#define CEX(av, ai, bv, bi)                                         \
  {                                                                 \
    const bool g_ = ((av) > (bv)) || ((av) == (bv) && (ai) < (bi)); \
    const float tv_ = g_ ? (av) : (bv);                             \
    const int ti_ = g_ ? (ai) : (bi);                               \
    (bv) = g_ ? (bv) : (av); (bi) = g_ ? (bi) : (ai);               \
    (av) = tv_; (ai) = ti_;                                         \
  }

// per-plane ushort stride of the presplit buffer
#define PSTRIDE ((size_t)BB * NL * NH * 1024 * 32)  // 2,097,152

// ---------------------------------------------------------------------------
// Kernel 0: one-shot bf16x3 split of value, head-major layout:
// vs[part][n][l][h][row(1024)][32] ushort.
// ---------------------------------------------------------------------------
__global__ __launch_bounds__(256) void vsplit_kernel(
    const float* __restrict__ value, ushort* __restrict__ vs) {
  const int T = blockIdx.x * 256 + threadIdx.x;  // < 262144
  const int flat = T << 3;
  const int n = flat >> 20;
  const int rem = flat & 0xFFFFF;
  const int lin = rem >> 8;
  const int d0 = rem & 255;
  const int l = lin >> 10, row = lin & 1023;
  const int h = d0 >> 5, dd = d0 & 31;

  const float* src = value + (size_t)flat;
  float xf[8];
  *(float4*)&xf[0] = *(const float4*)src;
  *(float4*)&xf[4] = *(const float4*)(src + 4);

  ushort uh[8], ul[8], ul2[8];
  #pragma unroll
  for (int j = 0; j < 8; ++j) {
    const float x = xf[j];
    const ushort h1 = bf16rn(x);
    const float r1 = x - bf16tof(h1);
    const ushort h2 = bf16rn(r1);
    const float r2 = r1 - bf16tof(h2);
    uh[j] = h1; ul[j] = h2; ul2[j] = bf16rn(r2);
  }
  const size_t ob = ((((size_t)((n * NL + l) * NH + h)) << 10) + row) * 32 + dd;
  *(bf16x8*)(vs + 0 * PSTRIDE + ob) =
      (bf16x8){(short)uh[0], (short)uh[1], (short)uh[2], (short)uh[3],
               (short)uh[4], (short)uh[5], (short)uh[6], (short)uh[7]};
  *(bf16x8*)(vs + 1 * PSTRIDE + ob) =
      (bf16x8){(short)ul[0], (short)ul[1], (short)ul[2], (short)ul[3],
               (short)ul[4], (short)ul[5], (short)ul[6], (short)ul[7]};
  *(bf16x8*)(vs + 2 * PSTRIDE + ob) =
      (bf16x8){(short)ul2[0], (short)ul2[1], (short)ul2[2], (short)ul2[3],
               (short)ul2[4], (short)ul2[5], (short)ul2[6], (short)ul2[7]};
}

// ---------------------------------------------------------------------------
// Kernel 1 (v12 = R8-winner v7 + corrected swizzle): corr + stable element
// top-4 via bf16x3 MFMA. LDS [64][32] ushort rows; slot swizzle
// s ^ ((row>>1)&3) on write and read -> 0 bank conflicts (measured R9-R12).
// PRESPLIT=1: stage pre-split planes (pure copy). PRESPLIT=0: convert
// in-kernel. SPLIT=2: blockIdx.x = qc*2+half, each block scans 512 k (8
// 64-row chunks), writes partial sorted (val,idx) lists; merge combines.
// Lane L: C col = q = L&15; rows k = base + (L>>4)*4 + reg.
// ---------------------------------------------------------------------------
template <int SPLIT, int PRESPLIT>
__global__ __launch_bounds__(256) void corr_topk_kernel(
    const float* __restrict__ query, const float* __restrict__ value,
    const ushort* __restrict__ vs, int* __restrict__ idx_out,
    float4* __restrict__ pval, int4* __restrict__ pidx) {
  __shared__ ushort hiL[64][32];
  __shared__ ushort loL[64][32];
  __shared__ ushort lo2L[64][32];

  const int tid = threadIdx.x;
  const int nh = blockIdx.z;  // n*8+h
  const int n = nh >> 3, h = nh & 7;
  const int l = blockIdx.y;
  const int qc = (SPLIT == 2) ? ((int)blockIdx.x >> 1) : (int)blockIdx.x;
  const int half = (SPLIT == 2) ? ((int)blockIdx.x & 1) : 0;
  const int c0 = (SPLIT == 2) ? (half << 3) : 0;  // 64-row chunks
  const int c1 = (SPLIT == 2) ? (c0 + 8) : 16;
  const int w = tid >> 6, L = tid & 63;
  const int qtile = (qc << 2) + w;     // 0..63
  const int r16 = L & 15, g = L >> 4;  // C: col=r16(q), row-group g

  // ---- Q: bf16x3 fragments (persistent) ----
  bf16x8 qhi, qlo, qlo2;
  {
    const float* qp =
        query + (size_t)(n * LQ + (qtile << 4) + r16) * DM + h * DH + (g << 3);
    float qf[8];
    *(float4*)&qf[0] = *(const float4*)qp;
    *(float4*)&qf[4] = *(const float4*)(qp + 4);
    ushort uh[8], ul[8], ul2[8];
    #pragma unroll
    for (int j = 0; j < 8; ++j) {
      const float x = qf[j];
      const ushort h1 = bf16rn(x);
      const float r1 = x - bf16tof(h1);
      const ushort h2 = bf16rn(r1);
      const float r2 = r1 - bf16tof(h2);
      uh[j] = h1; ul[j] = h2; ul2[j] = bf16rn(r2);
    }
    qhi = (bf16x8){(short)uh[0], (short)uh[1], (short)uh[2], (short)uh[3],
                   (short)uh[4], (short)uh[5], (short)uh[6], (short)uh[7]};
    qlo = (bf16x8){(short)ul[0], (short)ul[1], (short)ul[2], (short)ul[3],
                   (short)ul[4], (short)ul[5], (short)ul[6], (short)ul[7]};
    qlo2 = (bf16x8){(short)ul2[0], (short)ul2[1], (short)ul2[2], (short)ul2[3],
                    (short)ul2[4], (short)ul2[5], (short)ul2[6], (short)ul2[7]};
  }

  // element-level top-4 state (sorted desc, lexicographic)
  float v0 = -INFINITY, v1 = -INFINITY, v2 = -INFINITY, v3 = -INFINITY;
  int i0 = 0, i1 = 0, i2 = 0, i3 = 0;

  // staging mapping: thread -> (srow = tid>>2, s = tid&3); corrected swizzle
  const int srow = tid >> 2, s = tid & 3;
  const int wslot = (s ^ ((srow >> 1) & 3)) << 3;
  const int rslot = (g ^ ((r16 >> 1) & 3)) << 3;  // row&3 == r16&3 per tile
  const ushort* psbase =
      PRESPLIT ? vs + ((((size_t)((n * NL + l) * NH + h)) << 10)) * 32 : nullptr;
  const float* vbase = value + (size_t)(n * LIN + l * HWsp) * DM + h * DH;

  for (int c = c0; c < c1; ++c) {
    if (PRESPLIT) {
      const size_t off = ((size_t)((c << 6) + srow)) * 32 + (s << 3);
      *(bf16x8*)&hiL[srow][wslot] = *(const bf16x8*)(psbase + off);
      *(bf16x8*)&loL[srow][wslot] = *(const bf16x8*)(psbase + PSTRIDE + off);
      *(bf16x8*)&lo2L[srow][wslot] = *(const bf16x8*)(psbase + 2 * PSTRIDE + off);
    } else {
      const float* vp = vbase + (size_t)((c << 6) + srow) * DM + (s << 3);
      float xf[8];
      *(float4*)&xf[0] = *(const float4*)vp;
      *(float4*)&xf[4] = *(const float4*)(vp + 4);
      ushort uh[8], ul[8], ul2[8];
      #pragma unroll
      for (int j = 0; j < 8; ++j) {
        const float x = xf[j];
        const ushort h1 = bf16rn(x);
        const float r1 = x - bf16tof(h1);
        const ushort h2 = bf16rn(r1);
        const float r2 = r1 - bf16tof(h2);
        uh[j] = h1; ul[j] = h2; ul2[j] = bf16rn(r2);
      }
      *(bf16x8*)&hiL[srow][wslot] =
          (bf16x8){(short)uh[0], (short)uh[1], (short)uh[2], (short)uh[3],
                   (short)uh[4], (short)uh[5], (short)uh[6], (short)uh[7]};
      *(bf16x8*)&loL[srow][wslot] =
          (bf16x8){(short)ul[0], (short)ul[1], (short)ul[2], (short)ul[3],
                   (short)ul[4], (short)ul[5], (short)ul[6], (short)ul[7]};
      *(bf16x8*)&lo2L[srow][wslot] =
          (bf16x8){(short)ul2[0], (short)ul2[1], (short)ul2[2], (short)ul2[3],
                   (short)ul2[4], (short)ul2[5], (short)ul2[6], (short)ul2[7]};
    }
    __syncthreads();

    #pragma unroll
    for (int t = 0; t < 4; ++t) {
      const int row = (t << 4) + r16;
      const bf16x8 ahi = *(const bf16x8*)&hiL[row][rslot];
      const bf16x8 alo = *(const bf16x8*)&loL[row][rslot];
      const bf16x8 alo2 = *(const bf16x8*)&lo2L[row][rslot];
      f32x4 acc = {0.f, 0.f, 0.f, 0.f};
      // smallest-first accumulation (validated R5-R12 ordering)
      acc = __builtin_amdgcn_mfma_f32_16x16x32_bf16(alo2, qhi, acc, 0, 0, 0);
      acc = __builtin_amdgcn_mfma_f32_16x16x32_bf16(ahi, qlo2, acc, 0, 0, 0);
      acc = __builtin_amdgcn_mfma_f32_16x16x32_bf16(alo, qlo, acc, 0, 0, 0);
      acc = __builtin_amdgcn_mfma_f32_16x16x32_bf16(alo, qhi, acc, 0, 0, 0);
      acc = __builtin_amdgcn_mfma_f32_16x16x32_bf16(ahi, qlo, acc, 0, 0, 0);
      acc = __builtin_amdgcn_mfma_f32_16x16x32_bf16(ahi, qhi, acc, 0, 0, 0);
      const int kb = (c << 6) + (t << 4) + (g << 2);
      INSERT4(acc[0], kb + 0);
      INSERT4(acc[1], kb + 1);
      INSERT4(acc[2], kb + 2);
      INSERT4(acc[3], kb + 3);
    }
    __syncthreads();
  }

  // ---- merge the 4 row-groups of this q-column (lanes 16/32) ----
  #pragma unroll
  for (int m = 16; m < 64; m <<= 1) {
    const float b0 = __shfl_xor(v0, m);
    const float b1 = __shfl_xor(v1, m);
    const float b2 = __shfl_xor(v2, m);
    const float b3 = __shfl_xor(v3, m);
    const int j0 = __shfl_xor(i0, m);
    const int j1 = __shfl_xor(i1, m);
    const int j2 = __shfl_xor(i2, m);
    const int j3 = __shfl_xor(i3, m);
    LMAX(v0, i0, b3, j3);
    LMAX(v1, i1, b2, j2);
    LMAX(v2, i2, b1, j1);
    LMAX(v3, i3, b0, j0);
    CEX(v0, i0, v2, i2);
    CEX(v1, i1, v3, i3);
    CEX(v0, i0, v1, i1);
    CEX(v2, i2, v3, i3);
  }

  if (L < 16) {
    const int q = (qtile << 4) + L;
    const size_t gi = (((size_t)nh * NL + l) << 10) + q;
    if (SPLIT == 2) {
      pval[gi * 2 + half] = make_float4(v0, v1, v2, v3);
      pidx[gi * 2 + half] = make_int4(i0, i1, i2, i3);
    } else {
      ((int4*)idx_out)[gi] = make_int4(i0, i1, i2, i3);
    }
  }
}

// ---------------------------------------------------------------------------
// Kernel 1b (v12): merge the two k-half partial top-4 lists per group AND
// write the loc output directly (loc is a pure function of the final idx4).
// Per thread: 36 float2 = 288 B contiguous, stored as 18 float4.
// ---------------------------------------------------------------------------
__global__ __launch_bounds__(256) void merge_topk_loc_kernel(
    const float4* __restrict__ pval, const int4* __restrict__ pidx,
    int* __restrict__ idx_out, float* __restrict__ loc) {
  const int t = blockIdx.x * 256 + threadIdx.x;  // < NGRP
  const float4 av = pval[t * 2 + 0];
  const int4 ai = pidx[t * 2 + 0];
  const float4 bv = pval[t * 2 + 1];
  const int4 bi = pidx[t * 2 + 1];
  float w0 = av.x, w1 = av.y, w2 = av.z, w3 = av.w;
  int m0 = ai.x, m1 = ai.y, m2 = ai.z, m3 = ai.w;
  LMAX(w0, m0, bv.w, bi.w);
  LMAX(w1, m1, bv.z, bi.z);
  LMAX(w2, m2, bv.y, bi.y);
  LMAX(w3, m3, bv.x, bi.x);
  CEX(w0, m0, w2, m2);
  CEX(w1, m1, w3, m3);
  CEX(w0, m0, w1, m1);
  CEX(w2, m2, w3, m3);
  ((int4*)idx_out)[t] = make_int4(m0, m1, m2, m3);

  // decode group: gi = ((n*8+h)*4+l)*1024 + q
  const int q = t & 1023, l = (t >> 10) & 3, h = (t >> 12) & 7, n = t >> 15;
  // loc float2 base: (((n*1024+q)*8+h)*4+l)*36
  const size_t base2 =
      (size_t)(((((n << 10) + q) << 3) + h << 2) + l) * 36;
  float4* lp4 = (float4*)(loc + base2 * 2);  // 288B-aligned (36*8 = 288)
  const int idxs[4] = {m0, m1, m2, m3};
  #pragma unroll
  for (int dd = 0; dd < 9; ++dd) {
    const int delta = (dd / 3 - 1) * 32 + (dd % 3) - 1;
    float vv[8];
    #pragma unroll
    for (int p = 0; p < 4; ++p) {
      int res = idxs[p] + delta;
      res = min(max(res, 0), 961);
      vv[p * 2] = (float)(res >> 5) * 0.03125f;
      vv[p * 2 + 1] = (float)(res & 31) * 0.03125f;
    }
    lp4[dd * 2] = make_float4(vv[0], vv[1], vv[2], vv[3]);
    lp4[dd * 2 + 1] = make_float4(vv[4], vv[5], vv[6], vv[7]);
  }
}

// ---------------------------------------------------------------------------
// Kernel 2 (tier-4 fallback only): standalone loc from idx_buf.
// ---------------------------------------------------------------------------
__global__ __launch_bounds__(256) void loc_kernel(const int* __restrict__ idx_buf,
                                                  float* __restrict__ loc) {
  const int t = blockIdx.x * 256 + threadIdx.x;  // < 2359296
  const int k = t % 36;
  int rest = t / 36;
  const int l = rest & 3; rest >>= 2;
  const int h = rest & 7; rest >>= 3;
  const int q = rest & 1023;
  const int n = rest >> 10;
  const int p = k & 3, dd = k >> 2;  // delta-major: k = dd*4 + p
  const int idx = idx_buf[(((((n << 3) + h) * NL + l) << 10) + q) * 4 + p];
  const int delta = ((dd / 3) - 1) * 32 + (dd % 3) - 1;
  int res = idx + delta;
  res = min(max(res, 0), 961);
  const int W = res >> 5, H = res & 31;
  ((float2*)loc)[t] = make_float2((float)W * 0.03125f, (float)H * 0.03125f);
}

// ---------------------------------------------------------------------------
// Kernel 3: gather+average, wave-per-(n,q,h,l) (R7/R8-validated).
// ---------------------------------------------------------------------------
__global__ __launch_bounds__(256) void gather_kernel(
    const float* __restrict__ value, const int* __restrict__ idx_buf,
    float* __restrict__ acc_out) {
  __shared__ float4 red[NL][8];
  const int bh = blockIdx.x;  // (n*1024+q)*8 + h
  const int h = bh & 7;
  const int nq = bh >> 3;
  const int n = nq >> 10, q = nq & 1023;
  const int tid = threadIdx.x;
  const int l = tid >> 6;  // wave = level
  const int L = tid & 63;
  const int cp = L >> 3, d4 = L & 7;

  const int4 id4 =
      ((const int4*)idx_buf)[((((size_t)((n << 3) + h)) * NL + l) << 10) + q];
  const float4* vb4 =
      (const float4*)(value + (size_t)(n * LIN + l * HWsp) * DM + h * DH) + d4;

  float4 a = make_float4(0.f, 0.f, 0.f, 0.f);
  #pragma unroll
  for (int p = 0; p < 4; ++p) {
    const int idx = (p == 0) ? id4.x : (p == 1) ? id4.y : (p == 2) ? id4.z : id4.w;
    const int H0 = idx & 31, W0 = idx >> 5;
    if (H0 >= 2 && H0 <= 30 && W0 >= 2 && W0 <= 28) {
      const int idxT = (H0 << 5) + W0;
      const int c0i = cp << 1;
      const int ax0 = c0i & 3, ay = c0i >> 2;
      const int r0 = idxT + (ax0 - 2) * 32 + (ay - 2);
      const float wy = (ay == 1 || ay == 2) ? 2.f : 1.f;
      const float f0 = ((ax0 == 2) ? 2.f : 1.f) * wy;
      const float f1 = ((ax0 + 1 == 1) ? 2.f : 1.f) * wy;
      const float4 va = vb4[(size_t)r0 * 64];
      const float4 vbb = vb4[(size_t)(r0 + 32) * 64];
      a.x += f0 * va.x + f1 * vbb.x;
      a.y += f0 * va.y + f1 * vbb.y;
      a.z += f0 * va.z + f1 * vbb.z;
      a.w += f0 * va.w + f1 * vbb.w;
    } else {
      #pragma unroll
      for (int it = 0; it < 5; ++it) {
        const int u = cp + (it << 3);
        const int cell = u >> 2, corner = u & 3;
        const int dy = (cell >= 3) + (cell >= 6) - 1;
        const int dx = cell - (dy + 1) * 3 - 1;
        int res = idx + dy * 32 + dx;
        res = min(max(res, 0), 961);
        const int W = res >> 5, H = res & 31;
        const int cw = corner & 1, ch = corner >> 1;
        const bool ok = (u < 36) && (W >= cw) && (H >= ch);
        const int row = ok ? (((H - ch) << 5) + (W - cw)) : 0;
        const float wgt = ok ? 1.f : 0.f;
        const float4 v = vb4[(size_t)row * 64];
        a.x += wgt * v.x;
        a.y += wgt * v.y;
        a.z += wgt * v.z;
        a.w += wgt * v.w;
      }
    }
  }

  #pragma unroll
  for (int m = 8; m < 64; m <<= 1) {
    a.x += __shfl_xor(a.x, m);
    a.y += __shfl_xor(a.y, m);
    a.z += __shfl_xor(a.z, m);
    a.w += __shfl_xor(a.w, m);
  }
  if (L < 8) red[l][L] = a;
  __syncthreads();
  if (tid < 8) {
    const float4 s0 = red[0][tid], s1 = red[1][tid], s2 = red[2][tid],
                 s3 = red[3][tid];
    float4 o;
    o.x = (s0.x + s1.x + s2.x + s3.x) * (1.0f / 576.0f);
    o.y = (s0.y + s1.y + s2.y + s3.y) * (1.0f / 576.0f);
    o.z = (s0.z + s1.z + s2.z + s3.z) * (1.0f / 576.0f);
    o.w = (s0.w + s1.w + s2.w + s3.w) * (1.0f / 576.0f);
    ((float4*)(acc_out + (size_t)nq * DM + h * DH))[tid] = o;
  }
}

// ---------------------------------------------------------------------------
// Kernel 4: out = acc @ W^T + b.  256 blocks x 256 threads, 8 q-rows/block.
// ---------------------------------------------------------------------------
__global__ __launch_bounds__(256) void proj_kernel(
    const float* __restrict__ acc_in, const float* __restrict__ W,
    const float* __restrict__ bias, float* __restrict__ out) {
  __shared__ float la[8][256];
  const int qb = blockIdx.x << 3;
  const int tid = threadIdx.x;
  for (int i = tid; i < 8 * 256; i += 256)
    la[i >> 8][i & 255] = acc_in[((size_t)qb << 8) + i];
  __syncthreads();
  const float* wrow = W + (size_t)tid * 256;
  float s0 = 0.f, s1 = 0.f, s2 = 0.f, s3 = 0.f, s4 = 0.f, s5 = 0.f, s6 = 0.f, s7 = 0.f;
  for (int c0 = 0; c0 < 256; c0 += 4) {
    const float4 wv = *(const float4*)(wrow + c0);
    #define PROJ_STEP(qi, sreg)                                   \
      {                                                           \
        const float4 av = *(const float4*)&la[qi][c0];            \
        sreg = fmaf(wv.x, av.x, sreg);                            \
        sreg = fmaf(wv.y, av.y, sreg);                            \
        sreg = fmaf(wv.z, av.z, sreg);                            \
        sreg = fmaf(wv.w, av.w, sreg);                            \
      }
    PROJ_STEP(0, s0) PROJ_STEP(1, s1) PROJ_STEP(2, s2) PROJ_STEP(3, s3)
    PROJ_STEP(4, s4) PROJ_STEP(5, s5) PROJ_STEP(6, s6) PROJ_STEP(7, s7)
    #undef PROJ_STEP
  }
  const float bj = bias[tid];
  out[(size_t)(qb + 0) * 256 + tid] = s0 + bj;
  out[(size_t)(qb + 1) * 256 + tid] = s1 + bj;
  out[(size_t)(qb + 2) * 256 + tid] = s2 + bj;
  out[(size_t)(qb + 3) * 256 + tid] = s3 + bj;
  out[(size_t)(qb + 4) * 256 + tid] = s4 + bj;
  out[(size_t)(qb + 5) * 256 + tid] = s5 + bj;
  out[(size_t)(qb + 6) * 256 + tid] = s6 + bj;
  out[(size_t)(qb + 7) * 256 + tid] = s7 + bj;
}

// ---------------------------------------------------------------------------
extern "C" void kernel_launch(void* const* d_in, const int* in_sizes, int n_in,
                              void* d_out, int out_size, void* d_ws, size_t ws_size,
                              hipStream_t stream) {
  (void)in_sizes; (void)n_in; (void)out_size;
  const float* query = (const float*)d_in[0];
  const float* value = (const float*)d_in[2];
  const float* opw = (const float*)d_in[5];
  const float* opb = (const float*)d_in[6];

  float* out = (float*)d_out;               // [2,1024,256]
  float* loc = out + (size_t)BB * LQ * DM;  // [2,1024,8,4,36,2]

  const size_t SPLITB = 3 * PSTRIDE * sizeof(ushort);        // 12.58 MB
  const size_t PARTB = (size_t)NGRP * 2 * 16;                // 2 MB each
  const size_t IDXB = (size_t)NGRP * 4 * sizeof(int);        // 1 MB
  const size_t ACCB = (size_t)BB * LQ * DM * sizeof(float);  // 2 MB

  if (ws_size >= SPLITB + 2 * PARTB + IDXB + ACCB) {
    // tier 1 (R8 winner): presplit + k-split x2; merge+loc fused
    ushort* vsb = (ushort*)d_ws;
    float4* pval = (float4*)((char*)d_ws + SPLITB);
    int4* pidx = (int4*)((char*)d_ws + SPLITB + PARTB);
    int* idx_buf = (int*)((char*)d_ws + SPLITB + 2 * PARTB);
    float* acc_buf = (float*)((char*)d_ws + SPLITB + 2 * PARTB + IDXB);

    vsplit_kernel<<<dim3(1024), 256, 0, stream>>>(value, vsb);
    corr_topk_kernel<2, 1><<<dim3(32, NL, BB * NH), 256, 0, stream>>>(
        query, value, vsb, idx_buf, pval, pidx);
    merge_topk_loc_kernel<<<dim3(NGRP / 256), 256, 0, stream>>>(pval, pidx,
                                                                idx_buf, loc);
    gather_kernel<<<dim3(BB * LQ * NH), 256, 0, stream>>>(value, idx_buf, acc_buf);
    proj_kernel<<<dim3(BB * LQ / 8), 256, 0, stream>>>(acc_buf, opw, opb, out);
  } else if (ws_size >= 2 * PARTB + IDXB + ACCB) {
    // tier 2: in-kernel conversion + k-split x2; merge+loc fused
    float4* pval = (float4*)d_ws;
    int4* pidx = (int4*)((char*)d_ws + PARTB);
    int* idx_buf = (int*)((char*)d_ws + 2 * PARTB);
    float* acc_buf = (float*)((char*)d_ws + 2 * PARTB + IDXB);

    corr_topk_kernel<2, 0><<<dim3(32, NL, BB * NH), 256, 0, stream>>>(
        query, value, (const ushort*)nullptr, idx_buf, pval, pidx);
    merge_topk_loc_kernel<<<dim3(NGRP / 256), 256, 0, stream>>>(pval, pidx,
                                                                idx_buf, loc);
    gather_kernel<<<dim3(BB * LQ * NH), 256, 0, stream>>>(value, idx_buf, acc_buf);
    proj_kernel<<<dim3(BB * LQ / 8), 256, 0, stream>>>(acc_buf, opw, opb, out);
  } else {
    // tier 3: minimal workspace, single-pass + standalone loc
    int* idx_buf = (int*)d_ws;
    float* acc_buf = (float*)((char*)d_ws + IDXB);

    corr_topk_kernel<1, 0><<<dim3(16, NL, BB * NH), 256, 0, stream>>>(
        query, value, (const ushort*)nullptr, idx_buf, (float4*)nullptr,
        (int4*)nullptr);
    loc_kernel<<<dim3((BB * LQ * NH * NL * K9) / 256), 256, 0, stream>>>(idx_buf, loc);
    gather_kernel<<<dim3(BB * LQ * NH), 256, 0, stream>>>(value, idx_buf, acc_buf);
    proj_kernel<<<dim3(BB * LQ / 8), 256, 0, stream>>>(acc_buf, opw, opb, out);
  }
}